// Round 1
// baseline (111.928 us; speedup 1.0000x reference)
//
#include <hip/hip_runtime.h>

// Depthwise 3x3 box-average (1/9 kernel, zero padding) on NCHW fp32.
// x: (8, 512, 128, 128) fp32 -> treated as NC=4096 independent 128x128 images.
//
// Each thread owns a 4-wide column strip (float4) over a 32-row band.
// Horizontal neighbors come from wave shuffles; vertical from a 3-row
// rolling window of horizontal sums held in registers. Every input row
// is loaded as one coalesced float4 per lane; each input byte is read
// ~1.06x (row-band overlap), written exactly once.

#define IMG_H 128
#define IMG_W 128
#define ROWS_PER_THREAD 32
#define ROW_BANDS (IMG_H / ROWS_PER_THREAD)   // 4
#define X4_PER_ROW (IMG_W / 4)                // 32 strips of 4 columns

__device__ __forceinline__ float4 row_hsum(const float* __restrict__ src,
                                           int row, int x4, int lane_in_group) {
    float4 v = make_float4(0.f, 0.f, 0.f, 0.f);
    if (row >= 0 && row < IMG_H) {
        v = *reinterpret_cast<const float4*>(src + row * IMG_W + x4 * 4);
    }
    // Neighbor columns across lanes. All lanes execute the shuffles
    // (loads above are predicated, shuffles are not).
    float left  = __shfl_up(v.w, 1, 64);
    float right = __shfl_down(v.x, 1, 64);
    if (lane_in_group == 0)                 left  = 0.f;  // x = -1 zero pad
    if (lane_in_group == X4_PER_ROW - 1)    right = 0.f;  // x = 128 zero pad
    float4 h;
    h.x = left + v.x + v.y;
    h.y = v.x  + v.y + v.z;
    h.z = v.y  + v.z + v.w;
    h.w = v.z  + v.w + right;
    return h;
}

__global__ __launch_bounds__(256) void avg_conv_52931176956489_kernel(
        const float* __restrict__ x, float* __restrict__ out, int n_imgs) {
    int tid = blockIdx.x * blockDim.x + threadIdx.x;
    int x4  = tid & (X4_PER_ROW - 1);          // bits 0..4
    int rb  = (tid >> 5) & (ROW_BANDS - 1);    // bits 5..6
    int img = tid >> 7;                        // bits 7+
    if (img >= n_imgs) return;

    int lane_in_group = threadIdx.x & (X4_PER_ROW - 1);

    const float* src = x   + (size_t)img * (IMG_H * IMG_W);
    float*       dst = out + (size_t)img * (IMG_H * IMG_W);

    int r0 = rb * ROWS_PER_THREAD;

    float4 hm = row_hsum(src, r0 - 1, x4, lane_in_group);
    float4 hc = row_hsum(src, r0,     x4, lane_in_group);

    const float inv9 = 1.0f / 9.0f;
    #pragma unroll 4
    for (int y = r0; y < r0 + ROWS_PER_THREAD; ++y) {
        float4 hp = row_hsum(src, y + 1, x4, lane_in_group);
        float4 o;
        o.x = (hm.x + hc.x + hp.x) * inv9;
        o.y = (hm.y + hc.y + hp.y) * inv9;
        o.z = (hm.z + hc.z + hp.z) * inv9;
        o.w = (hm.w + hc.w + hp.w) * inv9;
        *reinterpret_cast<float4*>(dst + y * IMG_W + x4 * 4) = o;
        hm = hc;
        hc = hp;
    }
}

extern "C" void kernel_launch(void* const* d_in, const int* in_sizes, int n_in,
                              void* d_out, int out_size, void* d_ws, size_t ws_size,
                              hipStream_t stream) {
    const float* x = (const float*)d_in[0];
    float* out = (float*)d_out;

    int n_imgs = in_sizes[0] / (IMG_H * IMG_W);       // 4096
    int total_threads = n_imgs * ROW_BANDS * X4_PER_ROW;  // 128 per image
    int block = 256;
    int grid = (total_threads + block - 1) / block;

    avg_conv_52931176956489_kernel<<<grid, block, 0, stream>>>(x, out, n_imgs);
}

// Round 3
// 87.573 us; speedup vs baseline: 1.2781x; 1.2781x over previous
//
#include <hip/hip_runtime.h>

// Depthwise 3x3 box-average (1/9 kernel, zero padding) on NCHW fp32.
// x: (8, 512, 128, 128) fp32 -> 4096 independent 128x128 images.
//
// Each thread owns a 4-wide column strip (float4) over a 32-row band.
// Horizontal neighbors via wave shuffles; vertical via rolling window of
// horizontal sums in registers. 4-row software pipeline: 4 independent
// float4 loads are issued back-to-back each outer iteration so >=4 memory
// requests are in flight per wave. Stores are nontemporal via a native
// ext_vector type (__builtin_nontemporal_store rejects HIP_vector_type).

#define IMG_H 128
#define IMG_W 128
#define ROWS_PER_THREAD 32
#define ROW_BANDS (IMG_H / ROWS_PER_THREAD)   // 4
#define X4_PER_ROW (IMG_W / 4)                // 32 strips of 4 columns

typedef float nfloat4 __attribute__((ext_vector_type(4)));

__device__ __forceinline__ float4 load_row(const float* __restrict__ src,
                                           int row, int x4) {
    float4 v = make_float4(0.f, 0.f, 0.f, 0.f);
    if (row >= 0 && row < IMG_H) {
        v = *reinterpret_cast<const float4*>(src + row * IMG_W + x4 * 4);
    }
    return v;
}

__device__ __forceinline__ float4 hsum(float4 v, int lane_in_group) {
    float left  = __shfl_up(v.w, 1, 64);
    float right = __shfl_down(v.x, 1, 64);
    if (lane_in_group == 0)              left  = 0.f;  // x = -1 zero pad
    if (lane_in_group == X4_PER_ROW - 1) right = 0.f;  // x = 128 zero pad
    float4 h;
    h.x = left + v.x + v.y;
    h.y = v.x  + v.y + v.z;
    h.z = v.y  + v.z + v.w;
    h.w = v.z  + v.w + right;
    return h;
}

__device__ __forceinline__ nfloat4 vavg(float4 a, float4 b, float4 c) {
    const float inv9 = 1.0f / 9.0f;
    nfloat4 o;
    o.x = (a.x + b.x + c.x) * inv9;
    o.y = (a.y + b.y + c.y) * inv9;
    o.z = (a.z + b.z + c.z) * inv9;
    o.w = (a.w + b.w + c.w) * inv9;
    return o;
}

__global__ __launch_bounds__(256) void avg_conv_52931176956489_kernel(
        const float* __restrict__ x, float* __restrict__ out, int n_imgs) {
    int tid = blockIdx.x * blockDim.x + threadIdx.x;
    int x4  = tid & (X4_PER_ROW - 1);          // bits 0..4
    int rb  = (tid >> 5) & (ROW_BANDS - 1);    // bits 5..6
    int img = tid >> 7;                        // bits 7+
    if (img >= n_imgs) return;

    int lane_in_group = threadIdx.x & (X4_PER_ROW - 1);

    const float* src = x   + (size_t)img * (IMG_H * IMG_W);
    float*       dst = out + (size_t)img * (IMG_H * IMG_W);

    int r0 = rb * ROWS_PER_THREAD;

    // Prologue: rows r0-1 and r0.
    float4 vm = load_row(src, r0 - 1, x4);
    float4 vc = load_row(src, r0,     x4);
    float4 hm = hsum(vm, lane_in_group);
    float4 hc = hsum(vc, lane_in_group);

    #pragma unroll
    for (int y = r0; y < r0 + ROWS_PER_THREAD; y += 4) {
        // 4 independent loads issued back-to-back.
        float4 v1 = load_row(src, y + 1, x4);
        float4 v2 = load_row(src, y + 2, x4);
        float4 v3 = load_row(src, y + 3, x4);
        float4 v4 = load_row(src, y + 4, x4);

        float4 h1 = hsum(v1, lane_in_group);
        float4 h2 = hsum(v2, lane_in_group);
        float4 h3 = hsum(v3, lane_in_group);
        float4 h4 = hsum(v4, lane_in_group);

        nfloat4* o0 = reinterpret_cast<nfloat4*>(dst + (y + 0) * IMG_W + x4 * 4);
        nfloat4* o1 = reinterpret_cast<nfloat4*>(dst + (y + 1) * IMG_W + x4 * 4);
        nfloat4* o2 = reinterpret_cast<nfloat4*>(dst + (y + 2) * IMG_W + x4 * 4);
        nfloat4* o3 = reinterpret_cast<nfloat4*>(dst + (y + 3) * IMG_W + x4 * 4);
        __builtin_nontemporal_store(vavg(hm, hc, h1), o0);
        __builtin_nontemporal_store(vavg(hc, h1, h2), o1);
        __builtin_nontemporal_store(vavg(h1, h2, h3), o2);
        __builtin_nontemporal_store(vavg(h2, h3, h4), o3);

        hm = h3;
        hc = h4;
    }
}

extern "C" void kernel_launch(void* const* d_in, const int* in_sizes, int n_in,
                              void* d_out, int out_size, void* d_ws, size_t ws_size,
                              hipStream_t stream) {
    const float* x = (const float*)d_in[0];
    float* out = (float*)d_out;

    int n_imgs = in_sizes[0] / (IMG_H * IMG_W);            // 4096
    int total_threads = n_imgs * ROW_BANDS * X4_PER_ROW;   // 128 per image
    int block = 256;
    int grid = (total_threads + block - 1) / block;

    avg_conv_52931176956489_kernel<<<grid, block, 0, stream>>>(x, out, n_imgs);
}